// Round 16
// baseline (732.767 us; speedup 1.0000x reference)
//
#include <hip/hip_runtime.h>
#include <hip/hip_bf16.h>
#include <hip/hip_fp16.h>

#define BD 4
#define SS 4096
#define DD 1024
#define RTOT (BD*SS)   // 16384 total rows

typedef _Float16 f16;
typedef __attribute__((ext_vector_type(8))) _Float16 f16x8;
typedef __attribute__((ext_vector_type(4))) float f32x4;

static __device__ __forceinline__ unsigned short f2h(float f) {
  f16 h = (f16)f;
  return __builtin_bit_cast(unsigned short, h);
}
static __device__ __forceinline__ float h2f(unsigned short u) {
  return (float)__builtin_bit_cast(f16, u);
}

// async global->LDS, 16B/lane, wave-uniform LDS base + lane*16
static __device__ __forceinline__ void gload16(const void* g, void* l) {
  __builtin_amdgcn_global_load_lds(
      (const __attribute__((address_space(1))) unsigned int*)g,
      (__attribute__((address_space(3))) unsigned int*)l, 16, 0, 0);
}

// ---------------- split W into hi/lo f16 ----------------
__global__ void split_w_kernel(const float* __restrict__ W,
                               unsigned short* __restrict__ Wh,
                               unsigned short* __restrict__ Wl) {
  int i = (blockIdx.x * 256 + threadIdx.x) * 4;
  float4 x = *reinterpret_cast<const float4*>(W + i);
  ushort4 h, l;
  h.x = f2h(x.x); l.x = f2h(x.x - h2f(h.x));
  h.y = f2h(x.y); l.y = f2h(x.y - h2f(h.y));
  h.z = f2h(x.z); l.z = f2h(x.z - h2f(h.z));
  h.w = f2h(x.w); l.w = f2h(x.w - h2f(h.w));
  *reinterpret_cast<ushort4*>(Wh + i) = h;
  *reinterpret_cast<ushort4*>(Wl + i) = l;
}

// ---------------- unified projection: 256x256 tile, 512 thr, fused fp32->f16 A ----------
// TERMS: 1 (v: X*Wh) or 2 (q/k: X*Wh + X*Wl)
// EPI: 0 = f16 single row-major; 1 = K-concat kc[row][2048] (hi at +0, lo at +1024); 2 = vT
template<int TERMS, int EPI>
__global__ __launch_bounds__(512, 2)
void proj_one(const float* __restrict__ X,
              const unsigned short* __restrict__ Wh,
              const unsigned short* __restrict__ Wl,
              const float* __restrict__ bias,
              unsigned short* __restrict__ O1, unsigned short* __restrict__ O2)
{
  constexpr int OPS = 1 + TERMS;
  __shared__ unsigned short lds[2 * OPS][8192];
  const int tid = threadIdx.x, lane = tid & 63, wid = tid >> 6;
  const int t0 = blockIdx.x * 256;   // row tile
  const int n0 = blockIdx.y * 256;   // output-col tile

  const int sfr = (tid >> 2) & 15;
  const int scc = (tid & 3) ^ ((sfr >> 1) & 3);
  const int srowl = (tid >> 6) * 16 + sfr;
  const size_t arow0 = (size_t)(t0 + srowl) * DD;          // fp32 A rows
  const size_t arow1 = (size_t)(t0 + srowl + 128) * DD;
  const size_t boff  = (size_t)(n0 + srowl) * DD + scc * 8;
  const int l0s = tid * 8;
  const int l1s = 4096 + tid * 8;   // +128 rows

  float4 ar[4];

#define PBLOAD(cur, k0)  do { \
    gload16(Wh + boff + (k0),          &lds[(cur)*OPS+1][l0s]); \
    gload16(Wh + boff + 131072 + (k0), &lds[(cur)*OPS+1][l1s]); \
    if (TERMS == 2) { \
      gload16(Wl + boff + (k0),          &lds[(cur)*OPS+2][l0s]); \
      gload16(Wl + boff + 131072 + (k0), &lds[(cur)*OPS+2][l1s]); \
    } \
  } while (0)

#define PALOAD(k0) do { \
    ar[0] = *reinterpret_cast<const float4*>(X + arow0 + (k0) + scc * 8); \
    ar[1] = *reinterpret_cast<const float4*>(X + arow0 + (k0) + scc * 8 + 4); \
    ar[2] = *reinterpret_cast<const float4*>(X + arow1 + (k0) + scc * 8); \
    ar[3] = *reinterpret_cast<const float4*>(X + arow1 + (k0) + scc * 8 + 4); \
  } while (0)

#define PAWRITE(buf) do { \
    ushort4 u0, u1, u2, u3; \
    u0.x = f2h(ar[0].x); u0.y = f2h(ar[0].y); u0.z = f2h(ar[0].z); u0.w = f2h(ar[0].w); \
    u1.x = f2h(ar[1].x); u1.y = f2h(ar[1].y); u1.z = f2h(ar[1].z); u1.w = f2h(ar[1].w); \
    u2.x = f2h(ar[2].x); u2.y = f2h(ar[2].y); u2.z = f2h(ar[2].z); u2.w = f2h(ar[2].w); \
    u3.x = f2h(ar[3].x); u3.y = f2h(ar[3].y); u3.z = f2h(ar[3].z); u3.w = f2h(ar[3].w); \
    unsigned short* d0 = &lds[(buf)*OPS+0][l0s]; \
    *reinterpret_cast<ushort4*>(d0)     = u0; \
    *reinterpret_cast<ushort4*>(d0 + 4) = u1; \
    unsigned short* d1 = &lds[(buf)*OPS+0][l1s]; \
    *reinterpret_cast<ushort4*>(d1)     = u2; \
    *reinterpret_cast<ushort4*>(d1 + 4) = u3; \
  } while (0)

  const int wr = wid >> 2, wc = wid & 3;   // wave tile 128(row) x 64(col)
  const int rfr = lane & 15, rcc = lane >> 4;
  const int lp8 = (rfr * 4 + (rcc ^ ((rfr >> 1) & 3))) * 8;

  f32x4 acc[8][4] = {};

  int cur = 0;
  PBLOAD(0, 0);
  PALOAD(0);
  PAWRITE(0);
  __syncthreads();

  for (int t = 0; t < 32; ++t) {
    if (t < 31) { PBLOAD(cur ^ 1, (t + 1) * 32); PALOAD((t + 1) * 32); }

    f16x8 bhf[4], blf[4];
#pragma unroll
    for (int n = 0; n < 4; ++n) {
      bhf[n] = *reinterpret_cast<const f16x8*>(&lds[cur * OPS + 1][(wc * 4 + n) * 512 + lp8]);
      if (TERMS == 2)
        blf[n] = *reinterpret_cast<const f16x8*>(&lds[cur * OPS + 2][(wc * 4 + n) * 512 + lp8]);
    }
#pragma unroll
    for (int h = 0; h < 2; ++h) {
      f16x8 ahf[4];
#pragma unroll
      for (int m = 0; m < 4; ++m)
        ahf[m] = *reinterpret_cast<const f16x8*>(&lds[cur * OPS + 0][(wr * 8 + h * 4 + m) * 512 + lp8]);
      __builtin_amdgcn_s_setprio(1);
#pragma unroll
      for (int m = 0; m < 4; ++m)
#pragma unroll
        for (int n = 0; n < 4; ++n) {
          acc[h * 4 + m][n] = __builtin_amdgcn_mfma_f32_16x16x32_f16(ahf[m], bhf[n], acc[h * 4 + m][n], 0, 0, 0);
          if (TERMS == 2)
            acc[h * 4 + m][n] = __builtin_amdgcn_mfma_f32_16x16x32_f16(ahf[m], blf[n], acc[h * 4 + m][n], 0, 0, 0);
        }
      __builtin_amdgcn_s_setprio(0);
    }

    if (t < 31) PAWRITE(cur ^ 1);
    __syncthreads();
    cur ^= 1;
  }
#undef PBLOAD
#undef PALOAD
#undef PAWRITE

  const int col = lane & 15, rb = (lane >> 4) * 4;
#pragma unroll
  for (int m = 0; m < 8; ++m)
#pragma unroll
    for (int n = 0; n < 4; ++n) {
      int oc = n0 + wc * 64 + n * 16 + col;
      float bv = bias[oc];
      if (EPI == 2) {
        int tr = t0 + wr * 128 + m * 16 + rb;      // 4 consecutive rows
        int bb = tr >> 12, s = tr & (SS - 1);
        ushort4 h;
        h.x = f2h(acc[m][n][0] + bv);
        h.y = f2h(acc[m][n][1] + bv);
        h.z = f2h(acc[m][n][2] + bv);
        h.w = f2h(acc[m][n][3] + bv);
        *reinterpret_cast<ushort4*>(O1 + ((size_t)(bb * DD + oc)) * SS + s) = h;
      } else {
#pragma unroll
        for (int q = 0; q < 4; ++q) {
          int tr = t0 + wr * 128 + m * 16 + rb + q;
          float p = acc[m][n][q] + bv;
          if (EPI == 0) {
            O1[(size_t)tr * DD + oc] = f2h(p);
          } else {
            unsigned short h = f2h(p);
            O1[(size_t)tr * 2048 + oc] = h;                      // kc hi
            O1[(size_t)tr * 2048 + 1024 + oc] = f2h(p - h2f(h)); // kc lo
          }
        }
      }
    }
}

// ---------------- logits v7b: K-concat (K=2048) + 8-phase schedule (B-stride FIXED) ----
// LDS shorts layout: buf*32768 + {A:0,B:16384} + ksub*8192 + half*4096 + granule.
// In BYTES: buf*65536 + {A:0,B:32768} + ksub*16384 + half*8192 + granule*16.
__global__ __launch_bounds__(512, 2)
void logits_v7(const unsigned short* __restrict__ qf,
               const unsigned short* __restrict__ kc,
               float* __restrict__ out)
{
  __shared__ unsigned short lds[65536];   // 128KB
  const int tid = threadIdx.x, lane = tid & 63, wid = tid >> 6;

  int bid = blockIdx.x;
  int swz = (bid & 7) * 128 + (bid >> 3);
  const int b = swz >> 8;
  const int r = swz & 255;
  const int t0 = (r >> 4) * 256, s0 = (r & 15) * 256;

  const unsigned short* qB  = qf + (size_t)b * SS * DD;
  const unsigned short* kcB = kc + (size_t)b * SS * 2048;

  const int sfr = (tid >> 2) & 15;
  const int scc = (tid & 3) ^ ((sfr >> 1) & 3);
  const int srowl = (tid >> 6) * 16 + sfr;
  const size_t qrow0 = (size_t)(t0 + srowl) * DD + scc * 8;
  const size_t qrow1 = (size_t)(t0 + 128 + srowl) * DD + scc * 8;
  const size_t krow0 = (size_t)(s0 + srowl) * 2048 + scc * 8;
  const size_t krow1 = (size_t)(s0 + 128 + srowl) * 2048 + scc * 8;

#define SG_A(TT, s, kk) do { \
    gload16(qB + qrow0 + (kk), &lds[((TT)&1)*32768 + (s)*8192 +        tid*8]); \
    gload16(qB + qrow1 + (kk), &lds[((TT)&1)*32768 + (s)*8192 + 4096 + tid*8]); \
  } while (0)
#define SG_B(TT, s, kk) do { \
    gload16(kcB + krow0 + (kk), &lds[((TT)&1)*32768 + 16384 + (s)*8192 +        tid*8]); \
    gload16(kcB + krow1 + (kk), &lds[((TT)&1)*32768 + 16384 + (s)*8192 + 4096 + tid*8]); \
  } while (0)

  const int wr = wid >> 2, wc = wid & 3;
  const int rfr = lane & 15, rcc = lane >> 4;
  const int lp8 = (rfr * 4 + (rcc ^ ((rfr >> 1) & 3))) * 8;

  const unsigned ldsbase =
      (unsigned)(size_t)(__attribute__((address_space(3))) unsigned short*)&lds[0];
  const unsigned lane_off = (unsigned)(lp8 * 2);

  f32x4 acc[8][4] = {};

#define DSR(dst, addr) asm volatile("ds_read_b128 %0, %1" : "=&v"(dst) : "v"(addr))

  // prologue: T0 fully, then T1's B s0, A s0, B s1 (A s1 issued at T0.ph0)
  SG_A(0, 0, 0);  SG_B(0, 0, 0);  SG_A(0, 1, 32); SG_B(0, 1, 32);
  SG_B(1, 0, 64); SG_A(1, 0, 64); SG_B(1, 1, 96);
  asm volatile("s_waitcnt vmcnt(6)" ::: "memory");
  __builtin_amdgcn_s_barrier();

  for (int T = 0; T < 32; ++T) {
    const int c = T & 1;
    const unsigned abase = ldsbase + lane_off + (unsigned)(c * 65536 + wr * 8192);
    const unsigned bbase = ldsbase + lane_off +
        (unsigned)(c * 65536 + 32768 + (wc >> 1) * 8192 + (wc & 1) * 4096);
    f16x8 a0[4], a1[4], bf[4];

    // ---- ph0: ksub=0, h=0 ----
#pragma unroll
    for (int n = 0; n < 4; ++n) DSR(bf[n], bbase + (unsigned)(n * 1024));
#pragma unroll
    for (int m = 0; m < 4; ++m) DSR(a0[m], abase + (unsigned)(m * 1024));
    if (T + 1 < 32) { int TT = T + 1; SG_A(TT, 1, (unsigned)((TT * 64 + 32) & 1023)); }
    __builtin_amdgcn_s_barrier();
    asm volatile("s_waitcnt lgkmcnt(0)" ::: "memory");
    __builtin_amdgcn_sched_barrier(0);
    __builtin_amdgcn_s_setprio(1);
#pragma unroll
    for (int m = 0; m < 4; ++m)
#pragma unroll
      for (int n = 0; n < 4; ++n)
        acc[m][n] = __builtin_amdgcn_mfma_f32_16x16x32_f16(a0[m], bf[n], acc[m][n], 0, 0, 0);
    __builtin_amdgcn_s_setprio(0);
    __builtin_amdgcn_s_barrier();

    // ---- ph1: ksub=0, h=1 ----
#pragma unroll
    for (int m = 0; m < 4; ++m) DSR(a1[m], abase + (unsigned)((4 + m) * 1024));
    if (T + 2 < 32) { int TT = T + 2; SG_B(TT, 0, (unsigned)(TT * 64)); }
    __builtin_amdgcn_s_barrier();
    asm volatile("s_waitcnt lgkmcnt(0)" ::: "memory");
    __builtin_amdgcn_sched_barrier(0);
    __builtin_amdgcn_s_setprio(1);
#pragma unroll
    for (int m = 0; m < 4; ++m)
#pragma unroll
      for (int n = 0; n < 4; ++n)
        acc[4 + m][n] = __builtin_amdgcn_mfma_f32_16x16x32_f16(a1[m], bf[n], acc[4 + m][n], 0, 0, 0);
    __builtin_amdgcn_s_setprio(0);
    __builtin_amdgcn_s_barrier();

    // ---- ph2: ksub=1, h=0 ----  (B ksub stride = 16384 BYTES — fixed)
#pragma unroll
    for (int n = 0; n < 4; ++n) DSR(bf[n], bbase + (unsigned)(16384 + n * 1024));
#pragma unroll
    for (int m = 0; m < 4; ++m) DSR(a0[m], abase + (unsigned)(16384 + m * 1024));
    if (T + 2 < 32) { int TT = T + 2; SG_A(TT, 0, (unsigned)((TT * 64) & 1023)); }
    __builtin_amdgcn_s_barrier();
    asm volatile("s_waitcnt lgkmcnt(0)" ::: "memory");
    __builtin_amdgcn_sched_barrier(0);
    __builtin_amdgcn_s_setprio(1);
#pragma unroll
    for (int m = 0; m < 4; ++m)
#pragma unroll
      for (int n = 0; n < 4; ++n)
        acc[m][n] = __builtin_amdgcn_mfma_f32_16x16x32_f16(a0[m], bf[n], acc[m][n], 0, 0, 0);
    __builtin_amdgcn_s_setprio(0);
    __builtin_amdgcn_s_barrier();

    // ---- ph3: ksub=1, h=1 ----
#pragma unroll
    for (int m = 0; m < 4; ++m) DSR(a1[m], abase + (unsigned)(16384 + (4 + m) * 1024));
    if (T + 2 < 32) { int TT = T + 2; SG_B(TT, 1, (unsigned)(TT * 64 + 32)); }
    __builtin_amdgcn_s_barrier();
    asm volatile("s_waitcnt lgkmcnt(0)" ::: "memory");
    __builtin_amdgcn_sched_barrier(0);
    __builtin_amdgcn_s_setprio(1);
#pragma unroll
    for (int m = 0; m < 4; ++m)
#pragma unroll
      for (int n = 0; n < 4; ++n)
        acc[4 + m][n] = __builtin_amdgcn_mfma_f32_16x16x32_f16(a1[m], bf[n], acc[4 + m][n], 0, 0, 0);
    __builtin_amdgcn_s_setprio(0);
    if (T < 30) asm volatile("s_waitcnt vmcnt(6)" ::: "memory");
    else        asm volatile("s_waitcnt vmcnt(0)" ::: "memory");
    __builtin_amdgcn_s_barrier();
  }
#undef SG_A
#undef SG_B
#undef DSR

  const int col = lane & 15, rb = (lane >> 4) * 4;
#pragma unroll
  for (int m = 0; m < 8; ++m)
#pragma unroll
    for (int n = 0; n < 4; ++n) {
      int s = s0 + wc * 64 + n * 16 + col;
#pragma unroll
      for (int q = 0; q < 4; ++q) {
        int tr = t0 + wr * 128 + m * 16 + rb + q;
        out[((size_t)b * SS + tr) * SS + s] = acc[m][n][q];
      }
    }
}

// ---------------- row softmax in-place ----------------
__global__ __launch_bounds__(256)
void softmax_kernel(float* __restrict__ attn) {
  float* rp = attn + (size_t)blockIdx.x * SS;
  const int tid = threadIdx.x, lane = tid & 63, wid = tid >> 6;
  float v[16];
  float m = -1e30f;
#pragma unroll
  for (int i = 0; i < 4; ++i) {
    float4 x = *reinterpret_cast<const float4*>(rp + i * 1024 + tid * 4);
    v[i * 4 + 0] = x.x; v[i * 4 + 1] = x.y; v[i * 4 + 2] = x.z; v[i * 4 + 3] = x.w;
    m = fmaxf(m, fmaxf(fmaxf(x.x, x.y), fmaxf(x.z, x.w)));
  }
#pragma unroll
  for (int off = 32; off; off >>= 1) m = fmaxf(m, __shfl_xor(m, off));
  __shared__ float redm[4], reds[4];
  if (lane == 0) redm[wid] = m;
  __syncthreads();
  m = fmaxf(fmaxf(redm[0], redm[1]), fmaxf(redm[2], redm[3]));
  float sum = 0.f;
#pragma unroll
  for (int i = 0; i < 16; ++i) { v[i] = __expf(v[i] - m); sum += v[i]; }
#pragma unroll
  for (int off = 32; off; off >>= 1) sum += __shfl_xor(sum, off);
  if (lane == 0) reds[wid] = sum;
  __syncthreads();
  float inv = 1.0f / (reds[0] + reds[1] + reds[2] + reds[3]);
#pragma unroll
  for (int i = 0; i < 4; ++i) {
    float4 x;
    x.x = v[i * 4 + 0] * inv; x.y = v[i * 4 + 1] * inv;
    x.z = v[i * 4 + 2] * inv; x.w = v[i * 4 + 3] * inv;
    *reinterpret_cast<float4*>(rp + i * 1024 + tid * 4) = x;
  }
}

// ---------------- PV v5: 256(t) x 256(o), 512 thr, 8 waves, BK=64, dbuf, T14 A-split ----
__global__ __launch_bounds__(512)
void pv_v5(const float* __restrict__ attn, const unsigned short* __restrict__ vT,
           float* __restrict__ out)
{
  __shared__ unsigned short lds[8][8192];   // [dbuf*4: A_s0,A_s1,B_s0,B_s1][16KB] = 128KB
  const int tid = threadIdx.x, lane = tid & 63, wid = tid >> 6;

  int bid = blockIdx.x;                     // 256 blocks
  int swz = (bid & 7) * 32 + (bid >> 3);    // bijective XCD swizzle
  const int b = swz >> 6, rem = swz & 63;
  const int t0 = (rem >> 2) * 256;          // 16 t-tiles
  const int n0 = (rem & 3) * 256;           // 4 o-tiles
  const float* aB = attn + ((size_t)b * SS + t0) * SS;
  const unsigned short* vB = vT + ((size_t)b * DD + n0) * SS;

  const int sfr = (tid >> 2) & 15;
  const int scc = (tid & 3) ^ ((sfr >> 1) & 3);
  const int srowl = (tid >> 6) * 16 + sfr;
  const size_t row0 = (size_t)srowl * SS;
  const size_t row1 = (size_t)(srowl + 128) * SS;
  const int l0s = tid * 8, l1s = 4096 + tid * 8;

  const int wr = wid >> 2, wc = wid & 3;    // wave tile 128(t) x 64(o)
  const int rfr = lane & 15, rcc = lane >> 4;
  const int lp8 = (rfr * 4 + (rcc ^ ((rfr >> 1) & 3))) * 8;

  f32x4 acc[8][4] = {};
  float4 ar[8];

#define PV5_BLOAD(buf, k0) do { \
    gload16(vB + row0 + (k0) + scc * 8,      &lds[(buf)*4+2][l0s]); \
    gload16(vB + row1 + (k0) + scc * 8,      &lds[(buf)*4+2][l1s]); \
    gload16(vB + row0 + (k0) + 32 + scc * 8, &lds[(buf)*4+3][l0s]); \
    gload16(vB + row1 + (k0) + 32 + scc * 8, &lds[(buf)*4+3][l1s]); \
  } while (0)

#define PV5_ALOAD(k0) do { \
    ar[0] = *reinterpret_cast<const float4*>(aB + row0 + (k0) + scc * 8); \
    ar[1] = *reinterpret_cast<const float4*>(aB + row0 + (k0) + scc * 8 + 4); \
    ar[2] = *reinterpret_cast<const float4*>(aB + row1 + (k0) + scc * 8); \
    ar[3] = *reinterpret_cast<const float4*>(aB + row1 + (k0) + scc * 8 + 4); \
    ar[4] = *reinterpret_cast<const float4*>(aB + row0 + (k0) + 32 + scc * 8); \
    ar[5] = *reinterpret_cast<const float4*>(aB + row0 + (k0) + 32 + scc * 8 + 4); \
    ar[6] = *reinterpret_cast<const float4*>(aB + row1 + (k0) + 32 + scc * 8); \
    ar[7] = *reinterpret_cast<const float4*>(aB + row1 + (k0) + 32 + scc * 8 + 4); \
  } while (0)

#define PV5_AWRITE(buf) do { \
    _Pragma("unroll") \
    for (int p = 0; p < 4; ++p) { \
      int s = p >> 1, hh = p & 1; \
      ushort4 u0, u1; \
      u0.x = f2h(ar[p*2].x);   u0.y = f2h(ar[p*2].y); \
      u0.z = f2h(ar[p*2].z);   u0.w = f2h(ar[p*2].w); \
      u1.x = f2h(ar[p*2+1].x); u1.y = f2h(ar[p*2+1].y); \
      u1.z = f2h(ar[p*2+1].z); u1.w = f2h(ar[p*2+1].w); \
      unsigned short* d = &lds[(buf)*4 + s][(hh ? l1s : l0s)]; \
      *reinterpret_cast<ushort4*>(d)     = u0; \
      *reinterpret_cast<ushort4*>(d + 4) = u1; \
    } \
  } while (0)

  int cur = 0;
  PV5_BLOAD(0, 0);
  PV5_ALOAD(0);
  PV5_AWRITE(0);
  __syncthreads();

  for (int it = 0; it < 64; ++it) {
    if (it < 63) { PV5_BLOAD(cur ^ 1, (it + 1) * 64); PV5_ALOAD((it + 1) * 64); }

#pragma unroll
    for (int s = 0; s < 2; ++s) {
      f16x8 bf[4];
#pragma unroll
      for (int n = 0; n < 4; ++n)
        bf[n] = *reinterpret_cast<const f16x8*>(&lds[cur * 4 + 2 + s][(wc * 4 + n) * 512 + lp8]);
#pragma unroll
      for (int h = 0; h < 2; ++h) {
        f16x8 af[4];
#pragma unroll
        for (int m = 0; m < 4; ++m)
          af[m] = *reinterpret_cast<const f16x8*>(&lds[cur * 4 + s][(wr * 8 + h * 4 + m) * 512 + lp8]);
        __builtin_amdgcn_s_setprio(1);
#pragma unroll
        for (int m = 0; m < 4; ++m)
#pragma unroll
          for (int n = 0; n < 4; ++n)
            acc[h * 4 + m][n] = __builtin_amdgcn_mfma_f32_16x16x32_f16(af[m], bf[n], acc[h * 4 + m][n], 0, 0, 0);
        __builtin_amdgcn_s_setprio(0);
      }
    }

    if (it < 63) PV5_AWRITE(cur ^ 1);
    __syncthreads();
    cur ^= 1;
  }
#undef PV5_BLOAD
#undef PV5_ALOAD
#undef PV5_AWRITE

  const int col = lane & 15, rb = (lane >> 4) * 4;
#pragma unroll
  for (int m = 0; m < 8; ++m)
#pragma unroll
    for (int n = 0; n < 4; ++n) {
      int o = n0 + wc * 64 + n * 16 + col;
#pragma unroll
      for (int q = 0; q < 4; ++q) {
        int t = t0 + wr * 128 + m * 16 + rb + q;
        out[((size_t)b * SS + t) * DD + o] = acc[m][n][q];
      }
    }
}

extern "C" void kernel_launch(void* const* d_in, const int* in_sizes, int n_in,
                              void* d_out, int out_size, void* d_ws, size_t ws_size,
                              hipStream_t stream) {
  const float* query = (const float*)d_in[0];
  const float* key   = (const float*)d_in[1];
  const float* value = (const float*)d_in[2];
  const float* W     = (const float*)d_in[3];
  const float* bias  = (const float*)d_in[4];

  float* out  = (float*)d_out;                  // [B,S,D]
  float* attn = out + (size_t)BD * SS * DD;     // [B,S,S]

  // workspace (shorts): Whf,Wlf 2x2MB + qfb 33.5 + kc 67 + vT 33.5 ~= 140MB
  unsigned short* Whf = (unsigned short*)d_ws;
  unsigned short* Wlf = Whf + (size_t)DD * DD;
  unsigned short* qfb = Wlf + (size_t)DD * DD;
  unsigned short* kc  = qfb + (size_t)RTOT * DD;
  unsigned short* vT  = kc  + (size_t)RTOT * 2048;

  split_w_kernel<<<DD * DD / (256 * 4), 256, 0, stream>>>(W, Whf, Wlf);

  dim3 gp(RTOT / 256, DD / 256);
  proj_one<2, 0><<<gp, 512, 0, stream>>>(query, Whf, Wlf, bias, qfb, nullptr);
  proj_one<2, 1><<<gp, 512, 0, stream>>>(key,   Whf, Wlf, bias, kc,  nullptr);
  proj_one<1, 2><<<gp, 512, 0, stream>>>(value, Whf, nullptr, bias, vT, nullptr);

  logits_v7<<<(SS / 256) * (SS / 256) * BD, 512, 0, stream>>>(qfb, kc, attn);
  softmax_kernel<<<RTOT, 256, 0, stream>>>(attn);
  pv_v5<<<(SS / 256) * (DD / 256) * BD, 512, 0, stream>>>(attn, vT, out);
}

// Round 17
// 701.020 us; speedup vs baseline: 1.0453x; 1.0453x over previous
//
#include <hip/hip_runtime.h>
#include <hip/hip_bf16.h>
#include <hip/hip_fp16.h>

#define BD 4
#define SS 4096
#define DD 1024
#define RTOT (BD*SS)   // 16384 total rows

typedef _Float16 f16;
typedef __attribute__((ext_vector_type(8))) _Float16 f16x8;
typedef __attribute__((ext_vector_type(4))) float f32x4;

static __device__ __forceinline__ unsigned short f2h(float f) {
  f16 h = (f16)f;
  return __builtin_bit_cast(unsigned short, h);
}
static __device__ __forceinline__ float h2f(unsigned short u) {
  return (float)__builtin_bit_cast(f16, u);
}

// async global->LDS, 16B/lane, wave-uniform LDS base + lane*16
static __device__ __forceinline__ void gload16(const void* g, void* l) {
  __builtin_amdgcn_global_load_lds(
      (const __attribute__((address_space(1))) unsigned int*)g,
      (__attribute__((address_space(3))) unsigned int*)l, 16, 0, 0);
}

// ---------------- split W into hi/lo f16 ----------------
__global__ void split_w_kernel(const float* __restrict__ W,
                               unsigned short* __restrict__ Wh,
                               unsigned short* __restrict__ Wl) {
  int i = (blockIdx.x * 256 + threadIdx.x) * 4;
  float4 x = *reinterpret_cast<const float4*>(W + i);
  ushort4 h, l;
  h.x = f2h(x.x); l.x = f2h(x.x - h2f(h.x));
  h.y = f2h(x.y); l.y = f2h(x.y - h2f(h.y));
  h.z = f2h(x.z); l.z = f2h(x.z - h2f(h.z));
  h.w = f2h(x.w); l.w = f2h(x.w - h2f(h.w));
  *reinterpret_cast<ushort4*>(Wh + i) = h;
  *reinterpret_cast<ushort4*>(Wl + i) = l;
}

// ---------------- fused q+k projection: 256x256 tile, 512 thr, 2-term f16 -------------
// blockIdx.z = 0: write q single f16 row-major; z = 1: write k as f16 hi/lo row-major.
__global__ __launch_bounds__(512, 2)
void proj_qk2(const float* __restrict__ Xq, const float* __restrict__ Xk,
              const unsigned short* __restrict__ Wh,
              const unsigned short* __restrict__ Wl,
              const float* __restrict__ bias,
              unsigned short* __restrict__ Oq,
              unsigned short* __restrict__ Okh, unsigned short* __restrict__ Okl)
{
  __shared__ unsigned short lds[6][8192];   // 2 buf x {A, Wh, Wl} x 16KB = 96KB
  const int tid = threadIdx.x, lane = tid & 63, wid = tid >> 6;
  const int t0 = blockIdx.x * 256;
  const int n0 = blockIdx.y * 256;
  const float* X = blockIdx.z ? Xk : Xq;

  const int sfr = (tid >> 2) & 15;
  const int scc = (tid & 3) ^ ((sfr >> 1) & 3);
  const int srowl = (tid >> 6) * 16 + sfr;
  const size_t arow0 = (size_t)(t0 + srowl) * DD;
  const size_t arow1 = (size_t)(t0 + srowl + 128) * DD;
  const size_t boff  = (size_t)(n0 + srowl) * DD + scc * 8;
  const int l0s = tid * 8;
  const int l1s = 4096 + tid * 8;

  float4 ar[4];

#define PBLOAD(cur, k0)  do { \
    gload16(Wh + boff + (k0),          &lds[(cur)*3+1][l0s]); \
    gload16(Wh + boff + 131072 + (k0), &lds[(cur)*3+1][l1s]); \
    gload16(Wl + boff + (k0),          &lds[(cur)*3+2][l0s]); \
    gload16(Wl + boff + 131072 + (k0), &lds[(cur)*3+2][l1s]); \
  } while (0)

#define PALOAD(k0) do { \
    ar[0] = *reinterpret_cast<const float4*>(X + arow0 + (k0) + scc * 8); \
    ar[1] = *reinterpret_cast<const float4*>(X + arow0 + (k0) + scc * 8 + 4); \
    ar[2] = *reinterpret_cast<const float4*>(X + arow1 + (k0) + scc * 8); \
    ar[3] = *reinterpret_cast<const float4*>(X + arow1 + (k0) + scc * 8 + 4); \
  } while (0)

#define PAWRITE(buf) do { \
    ushort4 u0, u1, u2, u3; \
    u0.x = f2h(ar[0].x); u0.y = f2h(ar[0].y); u0.z = f2h(ar[0].z); u0.w = f2h(ar[0].w); \
    u1.x = f2h(ar[1].x); u1.y = f2h(ar[1].y); u1.z = f2h(ar[1].z); u1.w = f2h(ar[1].w); \
    u2.x = f2h(ar[2].x); u2.y = f2h(ar[2].y); u2.z = f2h(ar[2].z); u2.w = f2h(ar[2].w); \
    u3.x = f2h(ar[3].x); u3.y = f2h(ar[3].y); u3.z = f2h(ar[3].z); u3.w = f2h(ar[3].w); \
    unsigned short* d0 = &lds[(buf)*3+0][l0s]; \
    *reinterpret_cast<ushort4*>(d0)     = u0; \
    *reinterpret_cast<ushort4*>(d0 + 4) = u1; \
    unsigned short* d1 = &lds[(buf)*3+0][l1s]; \
    *reinterpret_cast<ushort4*>(d1)     = u2; \
    *reinterpret_cast<ushort4*>(d1 + 4) = u3; \
  } while (0)

  const int wr = wid >> 2, wc = wid & 3;
  const int rfr = lane & 15, rcc = lane >> 4;
  const int lp8 = (rfr * 4 + (rcc ^ ((rfr >> 1) & 3))) * 8;

  f32x4 acc[8][4] = {};

  int cur = 0;
  PBLOAD(0, 0);
  PALOAD(0);
  PAWRITE(0);
  __syncthreads();

  for (int t = 0; t < 32; ++t) {
    if (t < 31) { PBLOAD(cur ^ 1, (t + 1) * 32); PALOAD((t + 1) * 32); }

    f16x8 bhf[4], blf[4];
#pragma unroll
    for (int n = 0; n < 4; ++n) {
      bhf[n] = *reinterpret_cast<const f16x8*>(&lds[cur * 3 + 1][(wc * 4 + n) * 512 + lp8]);
      blf[n] = *reinterpret_cast<const f16x8*>(&lds[cur * 3 + 2][(wc * 4 + n) * 512 + lp8]);
    }
#pragma unroll
    for (int h = 0; h < 2; ++h) {
      f16x8 ahf[4];
#pragma unroll
      for (int m = 0; m < 4; ++m)
        ahf[m] = *reinterpret_cast<const f16x8*>(&lds[cur * 3 + 0][(wr * 8 + h * 4 + m) * 512 + lp8]);
      __builtin_amdgcn_s_setprio(1);
#pragma unroll
      for (int m = 0; m < 4; ++m)
#pragma unroll
        for (int n = 0; n < 4; ++n) {
          acc[h * 4 + m][n] = __builtin_amdgcn_mfma_f32_16x16x32_f16(ahf[m], bhf[n], acc[h * 4 + m][n], 0, 0, 0);
          acc[h * 4 + m][n] = __builtin_amdgcn_mfma_f32_16x16x32_f16(ahf[m], blf[n], acc[h * 4 + m][n], 0, 0, 0);
        }
      __builtin_amdgcn_s_setprio(0);
    }

    if (t < 31) PAWRITE(cur ^ 1);
    __syncthreads();
    cur ^= 1;
  }
#undef PBLOAD
#undef PALOAD
#undef PAWRITE

  const int col = lane & 15, rb = (lane >> 4) * 4;
#pragma unroll
  for (int m = 0; m < 8; ++m)
#pragma unroll
    for (int n = 0; n < 4; ++n) {
      int oc = n0 + wc * 64 + n * 16 + col;
      float bv = bias[oc];
#pragma unroll
      for (int q = 0; q < 4; ++q) {
        int tr = t0 + wr * 128 + m * 16 + rb + q;
        float p = acc[m][n][q] + bv;
        if (blockIdx.z == 0) {
          Oq[(size_t)tr * DD + oc] = f2h(p);
        } else {
          unsigned short h = f2h(p);
          Okh[(size_t)tr * DD + oc] = h;
          Okl[(size_t)tr * DD + oc] = f2h(p - h2f(h));
        }
      }
    }
}

// ---------------- v projection: 256x256 tile, 1-term f16, writes vT [b][o][s] ----------
__global__ __launch_bounds__(512, 2)
void proj_v1(const float* __restrict__ X,
             const unsigned short* __restrict__ Wh,
             const float* __restrict__ bias,
             unsigned short* __restrict__ vT)
{
  __shared__ unsigned short lds[4][8192];   // 2 buf x {A, Wh} x 16KB = 64KB
  const int tid = threadIdx.x, lane = tid & 63, wid = tid >> 6;
  const int t0 = blockIdx.x * 256;
  const int n0 = blockIdx.y * 256;

  const int sfr = (tid >> 2) & 15;
  const int scc = (tid & 3) ^ ((sfr >> 1) & 3);
  const int srowl = (tid >> 6) * 16 + sfr;
  const size_t arow0 = (size_t)(t0 + srowl) * DD;
  const size_t arow1 = (size_t)(t0 + srowl + 128) * DD;
  const size_t boff  = (size_t)(n0 + srowl) * DD + scc * 8;
  const int l0s = tid * 8;
  const int l1s = 4096 + tid * 8;

  float4 ar[4];

#define PBLOAD(cur, k0)  do { \
    gload16(Wh + boff + (k0),          &lds[(cur)*2+1][l0s]); \
    gload16(Wh + boff + 131072 + (k0), &lds[(cur)*2+1][l1s]); \
  } while (0)

#define PALOAD(k0) do { \
    ar[0] = *reinterpret_cast<const float4*>(X + arow0 + (k0) + scc * 8); \
    ar[1] = *reinterpret_cast<const float4*>(X + arow0 + (k0) + scc * 8 + 4); \
    ar[2] = *reinterpret_cast<const float4*>(X + arow1 + (k0) + scc * 8); \
    ar[3] = *reinterpret_cast<const float4*>(X + arow1 + (k0) + scc * 8 + 4); \
  } while (0)

#define PAWRITE(buf) do { \
    ushort4 u0, u1, u2, u3; \
    u0.x = f2h(ar[0].x); u0.y = f2h(ar[0].y); u0.z = f2h(ar[0].z); u0.w = f2h(ar[0].w); \
    u1.x = f2h(ar[1].x); u1.y = f2h(ar[1].y); u1.z = f2h(ar[1].z); u1.w = f2h(ar[1].w); \
    u2.x = f2h(ar[2].x); u2.y = f2h(ar[2].y); u2.z = f2h(ar[2].z); u2.w = f2h(ar[2].w); \
    u3.x = f2h(ar[3].x); u3.y = f2h(ar[3].y); u3.z = f2h(ar[3].z); u3.w = f2h(ar[3].w); \
    unsigned short* d0 = &lds[(buf)*2+0][l0s]; \
    *reinterpret_cast<ushort4*>(d0)     = u0; \
    *reinterpret_cast<ushort4*>(d0 + 4) = u1; \
    unsigned short* d1 = &lds[(buf)*2+0][l1s]; \
    *reinterpret_cast<ushort4*>(d1)     = u2; \
    *reinterpret_cast<ushort4*>(d1 + 4) = u3; \
  } while (0)

  const int wr = wid >> 2, wc = wid & 3;
  const int rfr = lane & 15, rcc = lane >> 4;
  const int lp8 = (rfr * 4 + (rcc ^ ((rfr >> 1) & 3))) * 8;

  f32x4 acc[8][4] = {};

  int cur = 0;
  PBLOAD(0, 0);
  PALOAD(0);
  PAWRITE(0);
  __syncthreads();

  for (int t = 0; t < 32; ++t) {
    if (t < 31) { PBLOAD(cur ^ 1, (t + 1) * 32); PALOAD((t + 1) * 32); }

    f16x8 bhf[4];
#pragma unroll
    for (int n = 0; n < 4; ++n)
      bhf[n] = *reinterpret_cast<const f16x8*>(&lds[cur * 2 + 1][(wc * 4 + n) * 512 + lp8]);
#pragma unroll
    for (int h = 0; h < 2; ++h) {
      f16x8 ahf[4];
#pragma unroll
      for (int m = 0; m < 4; ++m)
        ahf[m] = *reinterpret_cast<const f16x8*>(&lds[cur * 2 + 0][(wr * 8 + h * 4 + m) * 512 + lp8]);
      __builtin_amdgcn_s_setprio(1);
#pragma unroll
      for (int m = 0; m < 4; ++m)
#pragma unroll
        for (int n = 0; n < 4; ++n)
          acc[h * 4 + m][n] = __builtin_amdgcn_mfma_f32_16x16x32_f16(ahf[m], bhf[n], acc[h * 4 + m][n], 0, 0, 0);
      __builtin_amdgcn_s_setprio(0);
    }

    if (t < 31) PAWRITE(cur ^ 1);
    __syncthreads();
    cur ^= 1;
  }
#undef PBLOAD
#undef PALOAD
#undef PAWRITE

  const int col = lane & 15, rb = (lane >> 4) * 4;
#pragma unroll
  for (int m = 0; m < 8; ++m)
#pragma unroll
    for (int n = 0; n < 4; ++n) {
      int oc = n0 + wc * 64 + n * 16 + col;
      float bv = bias[oc];
      int tr = t0 + wr * 128 + m * 16 + rb;      // 4 consecutive rows
      int bb = tr >> 12, s = tr & (SS - 1);
      ushort4 h;
      h.x = f2h(acc[m][n][0] + bv);
      h.y = f2h(acc[m][n][1] + bv);
      h.z = f2h(acc[m][n][2] + bv);
      h.w = f2h(acc[m][n][3] + bv);
      *reinterpret_cast<ushort4*>(vT + ((size_t)(bb * DD + oc)) * SS + s) = h;
    }
}

// ---------------- logits v3: 2-term asymmetric f16 (qf single, k hi/lo) ----------------
__global__ __launch_bounds__(512, 2)
void logits_v3(const unsigned short* __restrict__ qf,
               const unsigned short* __restrict__ kh, const unsigned short* __restrict__ kl,
               float* __restrict__ out)
{
  __shared__ unsigned short lds[6][8192];   // [dbuf*3 ops][16KB each]
  const int tid = threadIdx.x, lane = tid & 63, wid = tid >> 6;

  int bid = blockIdx.x;
  int swz = (bid & 7) * 128 + (bid >> 3);
  const int b = swz >> 8;
  const int r = swz & 255;
  const int t0 = (r >> 4) * 256, s0 = (r & 15) * 256;

  const unsigned short* qB  = qf + (size_t)b * SS * DD;
  const unsigned short* khB = kh + (size_t)b * SS * DD;
  const unsigned short* klB = kl + (size_t)b * SS * DD;

  const int sfr = (tid >> 2) & 15;
  const int scc = (tid & 3) ^ ((sfr >> 1) & 3);
  const int srowl = (tid >> 6) * 16 + sfr;
  const size_t qoff0 = (size_t)(t0 + srowl) * DD + scc * 8;
  const size_t koff0 = (size_t)(s0 + srowl) * DD + scc * 8;
  const int l0s = tid * 8;
  const int l1s = 4096 + tid * 8;

#define STAGE(cur, k0)  do { \
    gload16(qB  + qoff0 + (k0),          &lds[(cur)*3+0][l0s]); \
    gload16(qB  + qoff0 + 131072 + (k0), &lds[(cur)*3+0][l1s]); \
    gload16(khB + koff0 + (k0),          &lds[(cur)*3+1][l0s]); \
    gload16(khB + koff0 + 131072 + (k0), &lds[(cur)*3+1][l1s]); \
    gload16(klB + koff0 + (k0),          &lds[(cur)*3+2][l0s]); \
    gload16(klB + koff0 + 131072 + (k0), &lds[(cur)*3+2][l1s]); \
  } while (0)

  const int wr = wid >> 2, wc = wid & 3;
  const int rfr = lane & 15, rcc = lane >> 4;
  const int lp8 = (rfr * 4 + (rcc ^ ((rfr >> 1) & 3))) * 8;

  f32x4 acc[8][4] = {};

  int cur = 0;
  STAGE(0, 0);
  __syncthreads();

  for (int t = 0; t < 32; ++t) {
    if (t < 31) STAGE(cur ^ 1, (t + 1) * 32);

    f16x8 bhf[4], blf[4];
#pragma unroll
    for (int n = 0; n < 4; ++n) {
      bhf[n] = *reinterpret_cast<const f16x8*>(&lds[cur * 3 + 1][(wc * 4 + n) * 512 + lp8]);
      blf[n] = *reinterpret_cast<const f16x8*>(&lds[cur * 3 + 2][(wc * 4 + n) * 512 + lp8]);
    }
#pragma unroll
    for (int h = 0; h < 2; ++h) {
      f16x8 ahf[4];
#pragma unroll
      for (int m = 0; m < 4; ++m)
        ahf[m] = *reinterpret_cast<const f16x8*>(&lds[cur * 3 + 0][(wr * 8 + h * 4 + m) * 512 + lp8]);
      __builtin_amdgcn_s_setprio(1);
#pragma unroll
      for (int m = 0; m < 4; ++m)
#pragma unroll
        for (int n = 0; n < 4; ++n) {
          acc[h * 4 + m][n] = __builtin_amdgcn_mfma_f32_16x16x32_f16(ahf[m], bhf[n], acc[h * 4 + m][n], 0, 0, 0);
          acc[h * 4 + m][n] = __builtin_amdgcn_mfma_f32_16x16x32_f16(ahf[m], blf[n], acc[h * 4 + m][n], 0, 0, 0);
        }
      __builtin_amdgcn_s_setprio(0);
    }
    __syncthreads();
    cur ^= 1;
  }
#undef STAGE

  const int col = lane & 15, rb = (lane >> 4) * 4;
#pragma unroll
  for (int m = 0; m < 8; ++m)
#pragma unroll
    for (int n = 0; n < 4; ++n) {
      int s = s0 + wc * 64 + n * 16 + col;
#pragma unroll
      for (int q = 0; q < 4; ++q) {
        int tr = t0 + wr * 128 + m * 16 + rb + q;
        out[((size_t)b * SS + tr) * SS + s] = acc[m][n][q];
      }
    }
}

// ---------------- row softmax in-place ----------------
__global__ __launch_bounds__(256)
void softmax_kernel(float* __restrict__ attn) {
  float* rp = attn + (size_t)blockIdx.x * SS;
  const int tid = threadIdx.x, lane = tid & 63, wid = tid >> 6;
  float v[16];
  float m = -1e30f;
#pragma unroll
  for (int i = 0; i < 4; ++i) {
    float4 x = *reinterpret_cast<const float4*>(rp + i * 1024 + tid * 4);
    v[i * 4 + 0] = x.x; v[i * 4 + 1] = x.y; v[i * 4 + 2] = x.z; v[i * 4 + 3] = x.w;
    m = fmaxf(m, fmaxf(fmaxf(x.x, x.y), fmaxf(x.z, x.w)));
  }
#pragma unroll
  for (int off = 32; off; off >>= 1) m = fmaxf(m, __shfl_xor(m, off));
  __shared__ float redm[4], reds[4];
  if (lane == 0) redm[wid] = m;
  __syncthreads();
  m = fmaxf(fmaxf(redm[0], redm[1]), fmaxf(redm[2], redm[3]));
  float sum = 0.f;
#pragma unroll
  for (int i = 0; i < 16; ++i) { v[i] = __expf(v[i] - m); sum += v[i]; }
#pragma unroll
  for (int off = 32; off; off >>= 1) sum += __shfl_xor(sum, off);
  if (lane == 0) reds[wid] = sum;
  __syncthreads();
  float inv = 1.0f / (reds[0] + reds[1] + reds[2] + reds[3]);
#pragma unroll
  for (int i = 0; i < 4; ++i) {
    float4 x;
    x.x = v[i * 4 + 0] * inv; x.y = v[i * 4 + 1] * inv;
    x.z = v[i * 4 + 2] * inv; x.w = v[i * 4 + 3] * inv;
    *reinterpret_cast<float4*>(rp + i * 1024 + tid * 4) = x;
  }
}

// ---------------- PV v5: 256(t) x 256(o), 512 thr, 8 waves, BK=64, dbuf, T14 A-split ----
__global__ __launch_bounds__(512)
void pv_v5(const float* __restrict__ attn, const unsigned short* __restrict__ vT,
           float* __restrict__ out)
{
  __shared__ unsigned short lds[8][8192];   // [dbuf*4: A_s0,A_s1,B_s0,B_s1][16KB] = 128KB
  const int tid = threadIdx.x, lane = tid & 63, wid = tid >> 6;

  int bid = blockIdx.x;                     // 256 blocks
  int swz = (bid & 7) * 32 + (bid >> 3);    // bijective XCD swizzle
  const int b = swz >> 6, rem = swz & 63;
  const int t0 = (rem >> 2) * 256;          // 16 t-tiles
  const int n0 = (rem & 3) * 256;           // 4 o-tiles
  const float* aB = attn + ((size_t)b * SS + t0) * SS;
  const unsigned short* vB = vT + ((size_t)b * DD + n0) * SS;

  const int sfr = (tid >> 2) & 15;
  const int scc = (tid & 3) ^ ((sfr >> 1) & 3);
  const int srowl = (tid >> 6) * 16 + sfr;
  const size_t row0 = (size_t)srowl * SS;
  const size_t row1 = (size_t)(srowl + 128) * SS;
  const int l0s = tid * 8, l1s = 4096 + tid * 8;

  const int wr = wid >> 2, wc = wid & 3;    // wave tile 128(t) x 64(o)
  const int rfr = lane & 15, rcc = lane >> 4;
  const int lp8 = (rfr * 4 + (rcc ^ ((rfr >> 1) & 3))) * 8;

  f32x4 acc[8][4] = {};
  float4 ar[8];

#define PV5_BLOAD(buf, k0) do { \
    gload16(vB + row0 + (k0) + scc * 8,      &lds[(buf)*4+2][l0s]); \
    gload16(vB + row1 + (k0) + scc * 8,      &lds[(buf)*4+2][l1s]); \
    gload16(vB + row0 + (k0) + 32 + scc * 8, &lds[(buf)*4+3][l0s]); \
    gload16(vB + row1 + (k0) + 32 + scc * 8, &lds[(buf)*4+3][l1s]); \
  } while (0)

#define PV5_ALOAD(k0) do { \
    ar[0] = *reinterpret_cast<const float4*>(aB + row0 + (k0) + scc * 8); \
    ar[1] = *reinterpret_cast<const float4*>(aB + row0 + (k0) + scc * 8 + 4); \
    ar[2] = *reinterpret_cast<const float4*>(aB + row1 + (k0) + scc * 8); \
    ar[3] = *reinterpret_cast<const float4*>(aB + row1 + (k0) + scc * 8 + 4); \
    ar[4] = *reinterpret_cast<const float4*>(aB + row0 + (k0) + 32 + scc * 8); \
    ar[5] = *reinterpret_cast<const float4*>(aB + row0 + (k0) + 32 + scc * 8 + 4); \
    ar[6] = *reinterpret_cast<const float4*>(aB + row1 + (k0) + 32 + scc * 8); \
    ar[7] = *reinterpret_cast<const float4*>(aB + row1 + (k0) + 32 + scc * 8 + 4); \
  } while (0)

#define PV5_AWRITE(buf) do { \
    _Pragma("unroll") \
    for (int p = 0; p < 4; ++p) { \
      int s = p >> 1, hh = p & 1; \
      ushort4 u0, u1; \
      u0.x = f2h(ar[p*2].x);   u0.y = f2h(ar[p*2].y); \
      u0.z = f2h(ar[p*2].z);   u0.w = f2h(ar[p*2].w); \
      u1.x = f2h(ar[p*2+1].x); u1.y = f2h(ar[p*2+1].y); \
      u1.z = f2h(ar[p*2+1].z); u1.w = f2h(ar[p*2+1].w); \
      unsigned short* d = &lds[(buf)*4 + s][(hh ? l1s : l0s)]; \
      *reinterpret_cast<ushort4*>(d)     = u0; \
      *reinterpret_cast<ushort4*>(d + 4) = u1; \
    } \
  } while (0)

  int cur = 0;
  PV5_BLOAD(0, 0);
  PV5_ALOAD(0);
  PV5_AWRITE(0);
  __syncthreads();

  for (int it = 0; it < 64; ++it) {
    if (it < 63) { PV5_BLOAD(cur ^ 1, (it + 1) * 64); PV5_ALOAD((it + 1) * 64); }

#pragma unroll
    for (int s = 0; s < 2; ++s) {
      f16x8 bf[4];
#pragma unroll
      for (int n = 0; n < 4; ++n)
        bf[n] = *reinterpret_cast<const f16x8*>(&lds[cur * 4 + 2 + s][(wc * 4 + n) * 512 + lp8]);
#pragma unroll
      for (int h = 0; h < 2; ++h) {
        f16x8 af[4];
#pragma unroll
        for (int m = 0; m < 4; ++m)
          af[m] = *reinterpret_cast<const f16x8*>(&lds[cur * 4 + s][(wr * 8 + h * 4 + m) * 512 + lp8]);
        __builtin_amdgcn_s_setprio(1);
#pragma unroll
        for (int m = 0; m < 4; ++m)
#pragma unroll
          for (int n = 0; n < 4; ++n)
            acc[h * 4 + m][n] = __builtin_amdgcn_mfma_f32_16x16x32_f16(af[m], bf[n], acc[h * 4 + m][n], 0, 0, 0);
        __builtin_amdgcn_s_setprio(0);
      }
    }

    if (it < 63) PV5_AWRITE(cur ^ 1);
    __syncthreads();
    cur ^= 1;
  }
#undef PV5_BLOAD
#undef PV5_ALOAD
#undef PV5_AWRITE

  const int col = lane & 15, rb = (lane >> 4) * 4;
#pragma unroll
  for (int m = 0; m < 8; ++m)
#pragma unroll
    for (int n = 0; n < 4; ++n) {
      int o = n0 + wc * 64 + n * 16 + col;
#pragma unroll
      for (int q = 0; q < 4; ++q) {
        int t = t0 + wr * 128 + m * 16 + rb + q;
        out[((size_t)b * SS + t) * DD + o] = acc[m][n][q];
      }
    }
}

extern "C" void kernel_launch(void* const* d_in, const int* in_sizes, int n_in,
                              void* d_out, int out_size, void* d_ws, size_t ws_size,
                              hipStream_t stream) {
  const float* query = (const float*)d_in[0];
  const float* key   = (const float*)d_in[1];
  const float* value = (const float*)d_in[2];
  const float* W     = (const float*)d_in[3];
  const float* bias  = (const float*)d_in[4];

  float* out  = (float*)d_out;                  // [B,S,D]
  float* attn = out + (size_t)BD * SS * DD;     // [B,S,S]

  // workspace (shorts): Whf,Wlf 2x2MB + qfb,khi,klo,vT 4x33.5MB ~= 138MB
  unsigned short* Whf = (unsigned short*)d_ws;
  unsigned short* Wlf = Whf + (size_t)DD * DD;
  unsigned short* qfb = Wlf + (size_t)DD * DD;
  unsigned short* khi = qfb + (size_t)RTOT * DD;
  unsigned short* klo = khi + (size_t)RTOT * DD;
  unsigned short* vT  = klo + (size_t)RTOT * DD;

  split_w_kernel<<<DD * DD / (256 * 4), 256, 0, stream>>>(W, Whf, Wlf);

  proj_qk2<<<dim3(RTOT / 256, DD / 256, 2), 512, 0, stream>>>(
      query, key, Whf, Wlf, bias, qfb, khi, klo);
  proj_v1<<<dim3(RTOT / 256, DD / 256), 512, 0, stream>>>(value, Whf, bias, vT);

  logits_v3<<<(SS / 256) * (SS / 256) * BD, 512, 0, stream>>>(qfb, khi, klo, attn);
  softmax_kernel<<<RTOT, 256, 0, stream>>>(attn);
  pv_v5<<<(SS / 256) * (DD / 256) * BD, 512, 0, stream>>>(attn, vT, out);
}